// Round 2
// baseline (479.967 us; speedup 1.0000x reference)
//
#include <hip/hip_runtime.h>

typedef unsigned short u16;
typedef __bf16 bf16x8 __attribute__((ext_vector_type(8)));
typedef float   f32x4 __attribute__((ext_vector_type(4)));
typedef unsigned short u16x8 __attribute__((ext_vector_type(8)));

// ---------- helpers ----------
__device__ __forceinline__ u16 f2bf(float f) {
    unsigned int u = __builtin_bit_cast(unsigned int, f);
    u = u + 0x7FFFu + ((u >> 16) & 1u);   // round-to-nearest-even
    return (u16)(u >> 16);
}
__device__ __forceinline__ float bf2f(u16 b) {
    return __builtin_bit_cast(float, ((unsigned int)b) << 16);
}
__device__ __forceinline__ void gload16(const void* g, void* l) {
    // async global->LDS, 16B per lane; HW dest = wave-uniform base + lane*16
    __builtin_amdgcn_global_load_lds(
        (__attribute__((address_space(1))) void*)g,
        (__attribute__((address_space(3))) void*)l,
        16, 0, 0);
}

// ---------- kernel 1: fp32 -> bf16 cast (h) ----------
__global__ __launch_bounds__(256) void cvt_bf16(const float* __restrict__ x,
                                                u16* __restrict__ y, int n8) {
    int i = blockIdx.x * 256 + threadIdx.x;
    if (i >= n8) return;
    const f32x4* xp = (const f32x4*)x + (size_t)i * 2;
    f32x4 a = xp[0], b = xp[1];
    u16x8 o;
    o[0]=f2bf(a[0]); o[1]=f2bf(a[1]); o[2]=f2bf(a[2]); o[3]=f2bf(a[3]);
    o[4]=f2bf(b[0]); o[5]=f2bf(b[1]); o[6]=f2bf(b[2]); o[7]=f2bf(b[3]);
    ((u16x8*)y)[i] = o;
}

// ---------- kernel 2: Wq [K][N] fp32 -> WqT [N][K] bf16 ----------
__global__ __launch_bounds__(256) void transpose_cvt(const float* __restrict__ W,
                                                     u16* __restrict__ Wt) {
    __shared__ u16 tile[64][65];
    const int c0 = blockIdx.x * 64;   // N dim
    const int r0 = blockIdx.y * 64;   // K dim
    const int col = threadIdx.x & 63;
    const int rb  = (threadIdx.x >> 6) * 16;
    #pragma unroll
    for (int rr = 0; rr < 16; ++rr)
        tile[rb + rr][col] = f2bf(W[(size_t)(r0 + rb + rr) * 1024 + c0 + col]);
    __syncthreads();
    const int k = threadIdx.x & 63;
    #pragma unroll
    for (int rr = 0; rr < 16; ++rr) {
        int n = c0 + rb + rr;
        Wt[(size_t)n * 1024 + r0 + k] = tile[k][rb + rr];
    }
}

// ---------- kernel 3: W2T[b][j][h*64+d] = sum_e M0[b,h,d,e]*Wo[h*64+e][j] ----------
__global__ __launch_bounds__(256) void build_w2t(const float* __restrict__ M0,
                                                 const float* __restrict__ Wo,
                                                 u16* __restrict__ W2T) {
    const int jq = blockIdx.x, h = blockIdx.y, b = blockIdx.z;
    const int tid = threadIdx.x;
    const int j = jq * 256 + tid;
    __shared__ float m0s[64 * 64];
    const float* m0p = M0 + ((size_t)b * 16 + h) * 4096;
    for (int i = tid; i < 4096; i += 256) m0s[i] = m0p[i];
    __syncthreads();
    float wo[64];
    #pragma unroll
    for (int e = 0; e < 64; ++e) wo[e] = Wo[(size_t)(h * 64 + e) * 1024 + j];
    u16* outp = W2T + (size_t)b * 1024 * 1024 + (size_t)j * 1024 + h * 64;
    #pragma unroll 1
    for (int d = 0; d < 64; ++d) {
        float s = 0.f;
        #pragma unroll
        for (int e = 0; e < 64; ++e) s += m0s[d * 64 + e] * wo[e];
        outp[d] = f2bf(s);
    }
}

// ---------- kernel 5: per-row 1/max(||row||,1e-12) from bf16 P ----------
__global__ __launch_bounds__(256) void rownorm(const u16* __restrict__ P,
                                               float* __restrict__ scale) {
    const int row = blockIdx.x * 4 + (threadIdx.x >> 6);
    const int lane = threadIdx.x & 63;
    const u16x8* p = (const u16x8*)(P + (size_t)row * 1024) + lane * 2;
    u16x8 a = p[0], b = p[1];
    float s = 0.f;
    #pragma unroll
    for (int j = 0; j < 8; ++j) { float f = bf2f(a[j]); s += f * f; }
    #pragma unroll
    for (int j = 0; j < 8; ++j) { float f = bf2f(b[j]); s += f * f; }
    #pragma unroll
    for (int off = 32; off > 0; off >>= 1) s += __shfl_down(s, off);
    if (lane == 0) scale[row] = 1.0f / fmaxf(sqrtf(s), 1e-12f);
}

// ---------- GEMM: C[M,N] = A[M,K] * Bt[N,K]^T, bf16 in, fp32 acc ----------
// m97 structure: 128x128 tile, BK=32, 4 waves each 64x64 (4x4 of 16x16x32 MFMA),
// global_load_lds width=16 staging, single LDS buffer, 2 barriers.
template <int HAS_SCALE, typename CT>
__global__ __launch_bounds__(256) void gemm_bt(const u16* __restrict__ A,
                                               const u16* __restrict__ Bt,
                                               CT* __restrict__ C,
                                               const float* __restrict__ scale,
                                               int M, int N, int K,
                                               int bt_batch_stride, int rpb_log2) {
    const int tid  = threadIdx.x;
    const int lane = tid & 63;
    const int w    = tid >> 6;
    const int wm   = w >> 1, wn = w & 1;
    const int n0 = blockIdx.x * 128;
    const int m0 = blockIdx.y * 128;

    __shared__ u16 As[128 * 32];
    __shared__ u16 Bs[128 * 32];

    const u16* Btb = Bt + (size_t)(m0 >> rpb_log2) * (size_t)bt_batch_stride;

    // staging: per wave 2 A-calls + 2 B-calls, each 64 lanes x 16B = 1KB (16 rows x 64B)
    const int srow0 = (w * 2 + 0) * 16 + (lane >> 2);
    const int srow1 = (w * 2 + 1) * 16 + (lane >> 2);
    const int schunk = (lane & 3) * 8;  // element offset within the 32-elem row
    const u16* ga0 = A   + (size_t)(m0 + srow0) * K + schunk;
    const u16* ga1 = A   + (size_t)(m0 + srow1) * K + schunk;
    const u16* gb0 = Btb + (size_t)(n0 + srow0) * K + schunk;
    const u16* gb1 = Btb + (size_t)(n0 + srow1) * K + schunk;
    u16* lA0 = As + (w * 2 + 0) * 512;  // 16 rows * 32 elems
    u16* lA1 = As + (w * 2 + 1) * 512;
    u16* lB0 = Bs + (w * 2 + 0) * 512;
    u16* lB1 = Bs + (w * 2 + 1) * 512;

    f32x4 acc[4][4] = {};
    const int kq = (lane >> 4) * 8;  // k-offset of this lane's fragment
    const int rm = lane & 15;

    #pragma unroll 1
    for (int k0 = 0; k0 < K; k0 += 32) {
        gload16(ga0, lA0); gload16(ga1, lA1);
        gload16(gb0, lB0); gload16(gb1, lB1);
        ga0 += 32; ga1 += 32; gb0 += 32; gb1 += 32;
        __syncthreads();  // drains vmcnt for global_load_lds, then barrier
        bf16x8 a[4], b[4];
        #pragma unroll
        for (int t = 0; t < 4; ++t) {
            a[t] = *(const bf16x8*)(As + (wm * 64 + t * 16 + rm) * 32 + kq);
            b[t] = *(const bf16x8*)(Bs + (wn * 64 + t * 16 + rm) * 32 + kq);
        }
        #pragma unroll
        for (int i = 0; i < 4; ++i)
            #pragma unroll
            for (int j = 0; j < 4; ++j)
                acc[i][j] = __builtin_amdgcn_mfma_f32_16x16x32_bf16(a[i], b[j], acc[i][j], 0, 0, 0);
        __syncthreads();  // protect LDS before next stage overwrites
    }

    // epilogue: C layout col=lane&15, row=(lane>>4)*4+reg  [m89-verified]
    float* ssc = (float*)As;  // reuse LDS for row scales
    if constexpr (HAS_SCALE) {
        if (tid < 128) ssc[tid] = scale[m0 + tid];
        __syncthreads();
    }
    const int cn = lane & 15;
    const int rq = (lane >> 4) * 4;
    #pragma unroll
    for (int i = 0; i < 4; ++i) {
        const int rbase = wm * 64 + i * 16 + rq;
        #pragma unroll
        for (int j = 0; j < 4; ++j) {
            const int col = n0 + wn * 64 + j * 16 + cn;
            #pragma unroll
            for (int r = 0; r < 4; ++r) {
                float x = acc[i][j][r];
                if constexpr (HAS_SCALE) x *= ssc[rbase + r];
                size_t off = (size_t)(m0 + rbase + r) * N + col;
                if constexpr (sizeof(CT) == 2) ((u16*)C)[off] = f2bf(x);
                else                           C[off] = x;
            }
        }
    }
}

// ---------- launch ----------
// B=4, S=8192, HID=PROJ=1024, NH=16, HD=64; M = B*S = 32768
//
// Workspace plan (R1 fix: previous round used 138 MiB of d_ws unchecked ->
// suspected d_ws overrun -> device fault/abort). Now only 74.1 MiB of d_ws:
//   - hbf (bf16 h, 64 MiB) lives in the FIRST HALF OF d_out. It is dead after
//     gemm1; gemm2 later overwrites all of d_out with the final fp32 output.
//     Stream ordering makes this safe (gemm1 completes before gemm2 starts).
extern "C" void kernel_launch(void* const* d_in, const int* in_sizes, int n_in,
                              void* d_out, int out_size, void* d_ws, size_t ws_size,
                              hipStream_t stream) {
    const float* h  = (const float*)d_in[0];   // [4,8192,1024]
    const float* Wq = (const float*)d_in[1];   // [1024,1024]
    const float* Wo = (const float*)d_in[7];   // [1024,1024]
    const float* M0 = (const float*)d_in[8];   // [4,16,64,64]
    float* out = (float*)d_out;

    char* ws = (char*)d_ws;
    u16*   hbf   = (u16*)d_out;                 // 67,108,864 B (first half of out)
    u16*   P     = (u16*)(ws);                  // 67,108,864 B
    u16*   WqT   = (u16*)(ws + 67108864);       //  2,097,152 B
    u16*   W2T   = (u16*)(ws + 69206016);       //  8,388,608 B
    float* scale = (float*)(ws + 77594624);     //    131,072 B  (end: 77,725,696)

    const int M = 32768, N = 1024, K = 1024;

    cvt_bf16<<<16384, 256, 0, stream>>>(h, hbf, (M * K) / 8);
    transpose_cvt<<<dim3(16, 16), 256, 0, stream>>>(Wq, WqT);
    build_w2t<<<dim3(4, 16, 4), 256, 0, stream>>>(M0, Wo, W2T);
    // P = h @ Wq (bf16 out, un-normalized)
    gemm_bt<0, u16><<<dim3(N / 128, M / 128), 256, 0, stream>>>(
        hbf, WqT, P, nullptr, M, N, K, 0, 0);
    rownorm<<<M / 4, 256, 0, stream>>>(P, scale);
    // out = scale[m] * (P @ W2T[batch]) ; batch = m >> 13  (overwrites hbf: dead)
    gemm_bt<1, float><<<dim3(N / 128, M / 128), 256, 0, stream>>>(
        P, W2T, out, scale, M, N, K, 1024 * 1024, 13);
}

// Round 3
// 443.049 us; speedup vs baseline: 1.0833x; 1.0833x over previous
//
#include <hip/hip_runtime.h>

typedef unsigned short u16;
typedef __bf16 bf16x8 __attribute__((ext_vector_type(8)));
typedef float   f32x4 __attribute__((ext_vector_type(4)));
typedef unsigned short u16x8 __attribute__((ext_vector_type(8)));

// ---------- helpers ----------
__device__ __forceinline__ u16 f2bf(float f) {
    unsigned int u = __builtin_bit_cast(unsigned int, f);
    u = u + 0x7FFFu + ((u >> 16) & 1u);   // round-to-nearest-even
    return (u16)(u >> 16);
}
__device__ __forceinline__ float bf2f(u16 b) {
    return __builtin_bit_cast(float, ((unsigned int)b) << 16);
}
__device__ __forceinline__ void gload16(const void* g, void* l) {
    __builtin_amdgcn_global_load_lds(
        (__attribute__((address_space(1))) void*)g,
        (__attribute__((address_space(3))) void*)l,
        16, 0, 0);
}

// ---------- kernel 1: fp32 -> bf16 cast (h) ----------
__global__ __launch_bounds__(256) void cvt_bf16(const float* __restrict__ x,
                                                u16* __restrict__ y, int n8) {
    int i = blockIdx.x * 256 + threadIdx.x;
    if (i >= n8) return;
    const f32x4* xp = (const f32x4*)x + (size_t)i * 2;
    f32x4 a = xp[0], b = xp[1];
    u16x8 o;
    o[0]=f2bf(a[0]); o[1]=f2bf(a[1]); o[2]=f2bf(a[2]); o[3]=f2bf(a[3]);
    o[4]=f2bf(b[0]); o[5]=f2bf(b[1]); o[6]=f2bf(b[2]); o[7]=f2bf(b[3]);
    ((u16x8*)y)[i] = o;
}

// ---------- kernel 2: Wq [K][N] fp32 -> WqT [N][K] bf16 ----------
__global__ __launch_bounds__(256) void transpose_cvt(const float* __restrict__ W,
                                                     u16* __restrict__ Wt) {
    __shared__ u16 tile[64][65];
    const int c0 = blockIdx.x * 64;
    const int r0 = blockIdx.y * 64;
    const int col = threadIdx.x & 63;
    const int rb  = (threadIdx.x >> 6) * 16;
    #pragma unroll
    for (int rr = 0; rr < 16; ++rr)
        tile[rb + rr][col] = f2bf(W[(size_t)(r0 + rb + rr) * 1024 + c0 + col]);
    __syncthreads();
    const int k = threadIdx.x & 63;
    #pragma unroll
    for (int rr = 0; rr < 16; ++rr) {
        int n = c0 + rb + rr;
        Wt[(size_t)n * 1024 + r0 + k] = tile[k][rb + rr];
    }
}

// ---------- kernel 3: W2T[b][j][h*64+d] = sum_e M0[b,h,d,e]*Wo[h*64+e][j] ----------
__global__ __launch_bounds__(256) void build_w2t(const float* __restrict__ M0,
                                                 const float* __restrict__ Wo,
                                                 u16* __restrict__ W2T) {
    const int jq = blockIdx.x, h = blockIdx.y, b = blockIdx.z;
    const int tid = threadIdx.x;
    const int j = jq * 256 + tid;
    __shared__ float m0s[64 * 64];
    const float* m0p = M0 + ((size_t)b * 16 + h) * 4096;
    for (int i = tid; i < 4096; i += 256) m0s[i] = m0p[i];
    __syncthreads();
    float wo[64];
    #pragma unroll
    for (int e = 0; e < 64; ++e) wo[e] = Wo[(size_t)(h * 64 + e) * 1024 + j];
    u16* outp = W2T + (size_t)b * 1024 * 1024 + (size_t)j * 1024 + h * 64;
    #pragma unroll 1
    for (int d = 0; d < 64; ++d) {
        float s = 0.f;
        #pragma unroll
        for (int e = 0; e < 64; ++e) s += m0s[d * 64 + e] * wo[e];
        outp[d] = f2bf(s);
    }
}

// ---------- GEMM: C[M,N] = A[M,K] * Bt[N,K]^T, bf16 in, fp32 acc ----------
// m97 structure + R3 XCD swizzle. 128x128 tile, BK=32, 4 waves of 64x64.
// ACC_SSQ (gemm1): accumulate per-row sum-of-squares into ssq[] (atomicAdd).
// HAS_SCALE (gemm2): multiply rows by 1/max(sqrt(ssq[row]),1e-12).
// Grid is 1-D 2048 blocks; hard-coded 256 m-tiles x 8 n-tiles; XCD = id&7
// (HW round-robin), so all 8 n-tiles of an m-tile land on ONE XCD -> A-tile
// is fetched into that XCD's L2 once and reused 8x.
template <int ACC_SSQ, int HAS_SCALE, typename CT>
__global__ __launch_bounds__(256) void gemm_bt(const u16* __restrict__ A,
                                               const u16* __restrict__ Bt,
                                               CT* __restrict__ C,
                                               float* __restrict__ ssq,
                                               int M, int N, int K,
                                               int bt_batch_stride, int rpb_log2) {
    const int tid  = threadIdx.x;
    const int lane = tid & 63;
    const int w    = tid >> 6;
    const int wm   = w >> 1, wn = w & 1;
    // XCD-aware swizzle: id = nt + 8*(mt_local + 32*xcd)
    const int id  = blockIdx.x;
    const int xcd = id & 7;
    const int loc = id >> 3;
    const int mt  = xcd * 32 + (loc >> 3);
    const int nt  = loc & 7;
    const int n0 = nt * 128;
    const int m0 = mt * 128;

    __shared__ u16 As[128 * 32];
    __shared__ u16 Bs[128 * 32];

    const u16* Btb = Bt + (size_t)(m0 >> rpb_log2) * (size_t)bt_batch_stride;

    const int srow0 = (w * 2 + 0) * 16 + (lane >> 2);
    const int srow1 = (w * 2 + 1) * 16 + (lane >> 2);
    const int schunk = (lane & 3) * 8;
    const u16* ga0 = A   + (size_t)(m0 + srow0) * K + schunk;
    const u16* ga1 = A   + (size_t)(m0 + srow1) * K + schunk;
    const u16* gb0 = Btb + (size_t)(n0 + srow0) * K + schunk;
    const u16* gb1 = Btb + (size_t)(n0 + srow1) * K + schunk;
    u16* lA0 = As + (w * 2 + 0) * 512;
    u16* lA1 = As + (w * 2 + 1) * 512;
    u16* lB0 = Bs + (w * 2 + 0) * 512;
    u16* lB1 = Bs + (w * 2 + 1) * 512;

    f32x4 acc[4][4] = {};
    const int kq = (lane >> 4) * 8;
    const int rm = lane & 15;

    #pragma unroll 1
    for (int k0 = 0; k0 < K; k0 += 32) {
        gload16(ga0, lA0); gload16(ga1, lA1);
        gload16(gb0, lB0); gload16(gb1, lB1);
        ga0 += 32; ga1 += 32; gb0 += 32; gb1 += 32;
        __syncthreads();
        bf16x8 a[4], b[4];
        #pragma unroll
        for (int t = 0; t < 4; ++t) {
            a[t] = *(const bf16x8*)(As + (wm * 64 + t * 16 + rm) * 32 + kq);
            b[t] = *(const bf16x8*)(Bs + (wn * 64 + t * 16 + rm) * 32 + kq);
        }
        #pragma unroll
        for (int i = 0; i < 4; ++i)
            #pragma unroll
            for (int j = 0; j < 4; ++j)
                acc[i][j] = __builtin_amdgcn_mfma_f32_16x16x32_bf16(a[i], b[j], acc[i][j], 0, 0, 0);
        __syncthreads();
    }

    // ---- epilogue ----  C layout: col=lane&15, row=(lane>>4)*4+reg [m89]
    float* lred = (float*)As;   // reuse LDS: 128 floats (row scales or row ssq)
    if constexpr (HAS_SCALE) {
        if (tid < 128) {
            float q = ssq[m0 + tid];
            lred[tid] = 1.0f / fmaxf(sqrtf(q), 1e-12f);
        }
        __syncthreads();
    }
    if constexpr (ACC_SSQ) {
        if (tid < 128) lred[tid] = 0.f;
        __syncthreads();
    }
    const int cn = lane & 15;
    const int rq = (lane >> 4) * 4;
    #pragma unroll
    for (int i = 0; i < 4; ++i) {
        const int rbase = wm * 64 + i * 16 + rq;
        #pragma unroll
        for (int r = 0; r < 4; ++r) {
            const size_t rowoff = (size_t)(m0 + rbase + r) * N;
            float s = 0.f;
            #pragma unroll
            for (int j = 0; j < 4; ++j) {
                float x = acc[i][j][r];
                if constexpr (HAS_SCALE) x *= lred[rbase + r];
                if constexpr (ACC_SSQ) s += x * x;
                const int col = n0 + wn * 64 + j * 16 + cn;
                if constexpr (sizeof(CT) == 2) ((u16*)C)[rowoff + col] = f2bf(x);
                else                           C[rowoff + col] = x;
            }
            if constexpr (ACC_SSQ) {
                // reduce over the 16 col-lanes (lane bits 0..3)
                s += __shfl_xor(s, 1);
                s += __shfl_xor(s, 2);
                s += __shfl_xor(s, 4);
                s += __shfl_xor(s, 8);
                if (cn == 0) atomicAdd(&lred[rbase + r], s);  // 2 waves (wn) share row
            }
        }
    }
    if constexpr (ACC_SSQ) {
        __syncthreads();
        if (tid < 128) atomicAdd(&ssq[m0 + tid], lred[tid]);  // 8 n-blocks per row
    }
}

// ---------- launch ----------
// B=4, S=8192, HID=PROJ=1024, NH=16, HD=64; M = B*S = 32768
// ws usage: 77.7 MiB. hbf lives in d_out's first half (dead after gemm1;
// gemm2 overwrites all of d_out — stream-ordered, safe).
extern "C" void kernel_launch(void* const* d_in, const int* in_sizes, int n_in,
                              void* d_out, int out_size, void* d_ws, size_t ws_size,
                              hipStream_t stream) {
    const float* h  = (const float*)d_in[0];   // [4,8192,1024]
    const float* Wq = (const float*)d_in[1];   // [1024,1024]
    const float* Wo = (const float*)d_in[7];   // [1024,1024]
    const float* M0 = (const float*)d_in[8];   // [4,16,64,64]
    float* out = (float*)d_out;

    char* ws = (char*)d_ws;
    u16*   hbf  = (u16*)d_out;                 // 67,108,864 B (first half of out)
    u16*   P    = (u16*)(ws);                  // 67,108,864 B
    u16*   WqT  = (u16*)(ws + 67108864);       //  2,097,152 B
    u16*   W2T  = (u16*)(ws + 69206016);       //  8,388,608 B
    float* ssq  = (float*)(ws + 77594624);     //    131,072 B  (end: 77,725,696)

    const int M = 32768, N = 1024, K = 1024;

    hipMemsetAsync(ssq, 0, M * sizeof(float), stream);   // graph-capture-safe
    cvt_bf16<<<16384, 256, 0, stream>>>(h, hbf, (M * K) / 8);
    transpose_cvt<<<dim3(16, 16), 256, 0, stream>>>(Wq, WqT);
    build_w2t<<<dim3(4, 16, 4), 256, 0, stream>>>(M0, Wo, W2T);
    // P = h @ Wq (bf16, un-normalized) + per-row ssq via atomics
    gemm_bt<1, 0, u16><<<2048, 256, 0, stream>>>(
        hbf, WqT, P, ssq, M, N, K, 0, 0);
    // out = (1/max(sqrt(ssq),1e-12))[m] * (P @ W2T[batch]) ; batch = m >> 13
    gemm_bt<0, 1, float><<<2048, 256, 0, stream>>>(
        P, W2T, out, ssq, M, N, K, 1024 * 1024, 13);
}